// Round 1
// baseline (25.160 us; speedup 1.0000x reference)
//
#include <hip/hip_runtime.h>
#include <hip/hip_bf16.h>

#define N_SHARD 4
#define PPP     512
#define NEG_N   1024
#define EMB     256
#define NROWS   (N_SHARD * PPP)   // 2048

typedef __attribute__((ext_vector_type(8))) short bf16x8;  // 8 bf16 (4 VGPRs)
typedef __attribute__((ext_vector_type(4))) float f32x4;   // 4 fp32 acc

__device__ __forceinline__ unsigned short f2bf(float f) {
    union { float f; unsigned int u; } v; v.f = f;
    // round-to-nearest-even bf16
    return (unsigned short)((v.u + 0x7FFFu + ((v.u >> 16) & 1u)) >> 16);
}

// One wave (64 lanes) per row: lanes each handle 4 consecutive floats (float4).
// waves [0, 2048): gather h,r,t rows; pos[n] = sum(h*r*t) in fp32; store bf16(h*r).
// waves [2048, 3072): gather shard-0 negative rows; store bf16(t_neg).
__global__ __launch_bounds__(256) void prep_kernel(
    const int* __restrict__ head, const int* __restrict__ relation,
    const int* __restrict__ tail, const int* __restrict__ negative,
    const float* __restrict__ ent, const float* __restrict__ rel,
    float* __restrict__ pos_out,
    unsigned short* __restrict__ hr_bf, unsigned short* __restrict__ t_bf)
{
    const int wave = blockIdx.x * 4 + (threadIdx.x >> 6);
    const int lane = threadIdx.x & 63;
    if (wave < NROWS) {
        const int n = wave;
        const int hi = head[n], ri = relation[n], ti = tail[n];
        const float4 h4 = ((const float4*)(ent + (size_t)hi * EMB))[lane];
        const float4 r4 = ((const float4*)(rel + (size_t)ri * EMB))[lane];
        const float4 t4 = ((const float4*)(ent + (size_t)ti * EMB))[lane];
        const float hrx = h4.x * r4.x, hry = h4.y * r4.y;
        const float hrz = h4.z * r4.z, hrw = h4.w * r4.w;
        ushort4 s = make_ushort4(f2bf(hrx), f2bf(hry), f2bf(hrz), f2bf(hrw));
        *(ushort4*)(hr_bf + (size_t)n * EMB + lane * 4) = s;
        float p = hrx * t4.x + hry * t4.y + hrz * t4.z + hrw * t4.w;
        #pragma unroll
        for (int off = 32; off > 0; off >>= 1) p += __shfl_down(p, off, 64);
        if (lane == 0) pos_out[n] = p;
    } else if (wave < NROWS + NEG_N) {
        const int m = wave - NROWS;
        const int idx = negative[m];   // negative[0][0][m]: only shard 0 is used
        const float4 t4 = ((const float4*)(ent + (size_t)idx * EMB))[lane];
        ushort4 s = make_ushort4(f2bf(t4.x), f2bf(t4.y), f2bf(t4.z), f2bf(t4.w));
        *(ushort4*)(t_bf + (size_t)m * EMB + lane * 4) = s;
    }
}

// C[n,m] = sum_k hr[n,k] * t_neg[m,k]   (A·B^T, both row-major (row,k))
// Wave computes a 16(M)x64(N) tile, K=256 in 8 MFMA steps of K=32.
// Block = 4 waves stacked along M -> 64x64 block tile.
// Grid = (2048/64, 1024/64) = (32, 16).
// Epilogue replicates each value into the 4 column-copies of the (2048,4096) output.
__global__ __launch_bounds__(256) void neg_gemm_kernel(
    const unsigned short* __restrict__ hr_bf,
    const unsigned short* __restrict__ t_bf,
    float* __restrict__ neg_out)
{
    const int wid  = threadIdx.x >> 6;
    const int lane = threadIdx.x & 63;
    const int r16  = lane & 15;
    const int half = lane >> 4;                 // 0..3: k-subgroup
    const int row_tile = blockIdx.x * 64 + wid * 16;
    const int col_tile = blockIdx.y * 64;

    // A fragment: row = (lane&15), k = (lane>>4)*8 + i  (8 contiguous bf16 = 16B)
    const bf16x8* ap  = (const bf16x8*)(hr_bf + (size_t)(row_tile + r16) * EMB + half * 8);
    const bf16x8* bp0 = (const bf16x8*)(t_bf + (size_t)(col_tile +  0 + r16) * EMB + half * 8);
    const bf16x8* bp1 = (const bf16x8*)(t_bf + (size_t)(col_tile + 16 + r16) * EMB + half * 8);
    const bf16x8* bp2 = (const bf16x8*)(t_bf + (size_t)(col_tile + 32 + r16) * EMB + half * 8);
    const bf16x8* bp3 = (const bf16x8*)(t_bf + (size_t)(col_tile + 48 + r16) * EMB + half * 8);

    f32x4 acc0 = {0.f, 0.f, 0.f, 0.f};
    f32x4 acc1 = acc0, acc2 = acc0, acc3 = acc0;
    #pragma unroll
    for (int kk = 0; kk < 8; ++kk) {            // advance k by 32 elems = 4 bf16x8
        bf16x8 a = ap[kk * 4];
        acc0 = __builtin_amdgcn_mfma_f32_16x16x32_bf16(a, bp0[kk * 4], acc0, 0, 0, 0);
        acc1 = __builtin_amdgcn_mfma_f32_16x16x32_bf16(a, bp1[kk * 4], acc1, 0, 0, 0);
        acc2 = __builtin_amdgcn_mfma_f32_16x16x32_bf16(a, bp2[kk * 4], acc2, 0, 0, 0);
        acc3 = __builtin_amdgcn_mfma_f32_16x16x32_bf16(a, bp3[kk * 4], acc3, 0, 0, 0);
    }

    // C/D layout: col = lane&15, row = (lane>>4)*4 + reg  [measured m89/m91]
    const int row_base = row_tile + half * 4;
    #pragma unroll
    for (int v = 0; v < 4; ++v) {
        float* orow = neg_out + (size_t)(row_base + v) * 4096;
        const float vals[4] = {acc0[v], acc1[v], acc2[v], acc3[v]};
        #pragma unroll
        for (int nf = 0; nf < 4; ++nf) {
            const int col = col_tile + nf * 16 + r16;
            const float val = vals[nf];
            orow[col]        = val;
            orow[col + 1024] = val;
            orow[col + 2048] = val;
            orow[col + 3072] = val;
        }
    }
}

extern "C" void kernel_launch(void* const* d_in, const int* in_sizes, int n_in,
                              void* d_out, int out_size, void* d_ws, size_t ws_size,
                              hipStream_t stream) {
    const int*   head     = (const int*)d_in[0];
    const int*   relation = (const int*)d_in[1];
    const int*   tail     = (const int*)d_in[2];
    const int*   negative = (const int*)d_in[3];
    const float* ent      = (const float*)d_in[4];
    const float* rel      = (const float*)d_in[5];

    float* pos_out = (float*)d_out;            // 2048
    float* neg_out = (float*)d_out + NROWS;    // 2048 * 4096

    unsigned short* hr_bf = (unsigned short*)d_ws;                  // 2048*256 bf16 = 1 MiB
    unsigned short* t_bf  = hr_bf + (size_t)NROWS * EMB;            // 1024*256 bf16 = 0.5 MiB

    // 3072 waves = 768 blocks of 4 waves
    prep_kernel<<<768, 256, 0, stream>>>(head, relation, tail, negative, ent, rel,
                                         pos_out, hr_bf, t_bf);
    neg_gemm_kernel<<<dim3(32, 16), 256, 0, stream>>>(hr_bf, t_bf, neg_out);
}